// Round 1
// baseline (477.263 us; speedup 1.0000x reference)
//
#include <hip/hip_runtime.h>
#include <hip/hip_bf16.h>

#define NEG 0.2f

// ---------------- edge histogram by dst ----------------
__global__ void hist_k(const int* __restrict__ ei, int* __restrict__ cnt, int E, int N){
  int e = blockIdx.x*blockDim.x + threadIdx.x;
  if (e < E) atomicAdd(&cnt[ei[E + e]], 1);       // dst = edge_index[1][e]
  else if (e < E + N) atomicAdd(&cnt[e - E], 1);  // self loop
}

// ---------------- exclusive scan (3 kernels) ----------------
__global__ void scan1_k(const int* __restrict__ in, int* __restrict__ out,
                        int* __restrict__ bsum, int n){
  __shared__ int sd[256];
  int t = threadIdx.x;
  int base = blockIdx.x*1024 + t*4;
  int v0=0,v1=0,v2=0,v3=0;
  if (base+0 < n) v0 = in[base+0];
  if (base+1 < n) v1 = in[base+1];
  if (base+2 < n) v2 = in[base+2];
  if (base+3 < n) v3 = in[base+3];
  int s = v0+v1+v2+v3;
  sd[t] = s; __syncthreads();
  for (int o=1;o<256;o<<=1){
    int x = (t>=o)? sd[t-o] : 0; __syncthreads();
    sd[t] += x; __syncthreads();
  }
  int excl = sd[t] - s;
  if (t==255) bsum[blockIdx.x] = sd[t];
  if (base+0 < n) out[base+0] = excl;  excl += v0;
  if (base+1 < n) out[base+1] = excl;  excl += v1;
  if (base+2 < n) out[base+2] = excl;  excl += v2;
  if (base+3 < n) out[base+3] = excl;
}

// single block, nb <= 128
__global__ void scan2_k(int* __restrict__ bsum, int nb){
  __shared__ int sd[128];
  int t = threadIdx.x;
  int v = (t<nb)? bsum[t] : 0;
  sd[t]=v; __syncthreads();
  for (int o=1;o<128;o<<=1){
    int x = (t>=o)? sd[t-o]:0; __syncthreads();
    sd[t] += x; __syncthreads();
  }
  if (t<nb) bsum[t] = sd[t]-v;   // exclusive
}

__global__ void addoff_k(int* __restrict__ off, const int* __restrict__ bsum,
                         int* __restrict__ cur, int n, int total){
  int i = blockIdx.x*blockDim.x + threadIdx.x;
  if (i < n){ int v = off[i] + bsum[i>>10]; off[i]=v; cur[i]=v; }
  if (i==0) off[n] = total;
}

__global__ void scatter_k(const int* __restrict__ ei, int* __restrict__ cur,
                          int* __restrict__ ssrc, int E, int N){
  int e = blockIdx.x*blockDim.x + threadIdx.x;
  if (e < E){
    int s = ei[e], d = ei[E+e];
    int p = atomicAdd(&cur[d],1);
    ssrc[p] = s;
  } else if (e < E+N){
    int nn = e-E;
    int p = atomicAdd(&cur[nn],1);
    ssrc[p] = nn;
  }
}

// ---------------- h1 = x @ W1  (fp32, LDS tiles) ----------------
// tile: 128 rows x 128 cols, 256 threads, 8x8 outputs/thread.
// thread rows: ty + 16*i (bank-conflict-free with +4 row pad), cols: 4*tx and 64+4*tx.
__global__ __launch_bounds__(256) void gemm_k(const float* __restrict__ x,
                                              const float* __restrict__ W,
                                              float* __restrict__ h1, int N){
  __shared__ float xs[128*132];   // 67.6 KB (pad 4 floats/row)
  __shared__ float ws[128*128];   // 64 KB
  int tid = threadIdx.x;
  #pragma unroll
  for (int i=0;i<16;i++){
    int j = i*256 + tid;                       // 4096 float4s
    ((float4*)ws)[j] = ((const float4*)W)[j];
  }
  int rowBase = blockIdx.x * 128;
  #pragma unroll
  for (int i=0;i<16;i++){
    int j = i*256 + tid;                       // 128 rows x 32 float4
    int r = j >> 5, k4 = j & 31;
    float4 v = make_float4(0.f,0.f,0.f,0.f);
    if (rowBase + r < N) v = ((const float4*)x)[(size_t)(rowBase+r)*32 + k4];
    *(float4*)&xs[r*132 + k4*4] = v;
  }
  __syncthreads();
  int ty = tid >> 4, tx = tid & 15;
  float acc[8][8];
  #pragma unroll
  for (int i=0;i<8;i++)
    #pragma unroll
    for (int j=0;j<8;j++) acc[i][j]=0.f;
  for (int k=0;k<128;k+=4){
    float4 xv[8];
    #pragma unroll
    for (int i=0;i<8;i++) xv[i] = *(float4*)&xs[(ty + 16*i)*132 + k];
    #pragma unroll
    for (int j=0;j<4;j++){
      float4 wa = *(float4*)&ws[(k+j)*128 + tx*4];
      float4 wb = *(float4*)&ws[(k+j)*128 + 64 + tx*4];
      #pragma unroll
      for (int i=0;i<8;i++){
        float xx = ((float*)&xv[i])[j];
        acc[i][0] = fmaf(xx, wa.x, acc[i][0]);
        acc[i][1] = fmaf(xx, wa.y, acc[i][1]);
        acc[i][2] = fmaf(xx, wa.z, acc[i][2]);
        acc[i][3] = fmaf(xx, wa.w, acc[i][3]);
        acc[i][4] = fmaf(xx, wb.x, acc[i][4]);
        acc[i][5] = fmaf(xx, wb.y, acc[i][5]);
        acc[i][6] = fmaf(xx, wb.z, acc[i][6]);
        acc[i][7] = fmaf(xx, wb.w, acc[i][7]);
      }
    }
  }
  #pragma unroll
  for (int i=0;i<8;i++){
    int r = rowBase + ty + 16*i;
    if (r < N){
      *(float4*)&h1[(size_t)r*128 + tx*4]      = *(float4*)&acc[i][0];
      *(float4*)&h1[(size_t)r*128 + 64 + tx*4] = *(float4*)&acc[i][4];
    }
  }
}

// ---------------- per-node attention logits: a_src1/a_dst1 [N][2] ----------------
__global__ __launch_bounds__(64) void a1_k(const float* __restrict__ h1,
                                           const float* __restrict__ aw_s,
                                           const float* __restrict__ aw_d,
                                           float* __restrict__ as1, float* __restrict__ ad1, int N){
  int n = blockIdx.x; int l = threadIdx.x;
  float v0 = h1[(size_t)n*128 + l];        // head 0, channel l
  float v1 = h1[(size_t)n*128 + 64 + l];   // head 1, channel l
  float s0 = v0*aw_s[l],    s1 = v1*aw_s[64+l];
  float d0 = v0*aw_d[l],    d1 = v1*aw_d[64+l];
  #pragma unroll
  for (int o=32;o>0;o>>=1){
    s0 += __shfl_xor(s0,o); s1 += __shfl_xor(s1,o);
    d0 += __shfl_xor(d0,o); d1 += __shfl_xor(d1,o);
  }
  if (l==0){ as1[2*n]=s0; as1[2*n+1]=s1; ad1[2*n]=d0; ad1[2*n+1]=d1; }
}

// ---------------- layer-1 softmax + aggregation, fused bias/ReLU/W2-dot -> h2[n] ----------------
__global__ __launch_bounds__(64) void agg1_k(const float* __restrict__ h1,
                                             const float* __restrict__ as1,
                                             const float* __restrict__ ad1,
                                             const int* __restrict__ off,
                                             const int* __restrict__ ssrc,
                                             const float* __restrict__ b1,
                                             const float* __restrict__ W2,
                                             float* __restrict__ h2, int N){
  int n = blockIdx.x; int l = threadIdx.x;
  int beg = off[n], end = off[n+1];
  float adh0 = ad1[2*n], adh1 = ad1[2*n+1];
  // pass 1: per-head max (lane-strided over edges)
  float m0=-1e30f, m1=-1e30f;
  for (int k=beg+l; k<end; k+=64){
    int s = ssrc[k];
    float e0 = as1[2*s]   + adh0; e0 = (e0>0.f)? e0 : NEG*e0;
    float e1 = as1[2*s+1] + adh1; e1 = (e1>0.f)? e1 : NEG*e1;
    m0 = fmaxf(m0,e0); m1 = fmaxf(m1,e1);
  }
  #pragma unroll
  for (int o=32;o>0;o>>=1){ m0=fmaxf(m0,__shfl_xor(m0,o)); m1=fmaxf(m1,__shfl_xor(m1,o)); }
  // pass 2: serial over edges, lanes own channels (l and l+64)
  float den0=0.f, den1=0.f, acc0=0.f, acc1=0.f;
  for (int k=beg; k<end; k++){
    int s = ssrc[k];                      // uniform across wave -> broadcast load
    float e0 = as1[2*s]   + adh0; e0 = (e0>0.f)? e0 : NEG*e0;
    float e1 = as1[2*s+1] + adh1; e1 = (e1>0.f)? e1 : NEG*e1;
    float x0 = __expf(e0-m0), x1 = __expf(e1-m1);
    den0 += x0; den1 += x1;
    acc0 += x0 * h1[(size_t)s*128 + l];        // coalesced 256B
    acc1 += x1 * h1[(size_t)s*128 + 64 + l];   // coalesced 256B
  }
  float v0 = fmaxf(acc0/den0 + b1[l],    0.f);
  float v1 = fmaxf(acc1/den1 + b1[64+l], 0.f);
  float p = v0*W2[l] + v1*W2[64+l];            // layer-2 projection (C=1)
  #pragma unroll
  for (int o=32;o>0;o>>=1) p += __shfl_xor(p,o);
  if (l==0) h2[n] = p;
}

// ---------------- layer 2: scalar GAT + sigmoid ----------------
__global__ __launch_bounds__(256) void agg2_k(const float* __restrict__ h2,
                                              const int* __restrict__ off,
                                              const int* __restrict__ ssrc,
                                              const float* __restrict__ att_s2,
                                              const float* __restrict__ att_d2,
                                              const float* __restrict__ b2,
                                              float* __restrict__ out, int N){
  int w = threadIdx.x >> 6, l = threadIdx.x & 63;
  int n = blockIdx.x*4 + w;
  if (n >= N) return;
  float as2 = att_s2[0], ad2 = att_d2[0];
  int beg = off[n], end = off[n+1];
  float hd = h2[n]*ad2;
  float m = -1e30f;
  for (int k=beg+l; k<end; k+=64){
    float e = h2[ssrc[k]]*as2 + hd; e = (e>0.f)? e : NEG*e;
    m = fmaxf(m, e);
  }
  #pragma unroll
  for (int o=32;o>0;o>>=1) m = fmaxf(m, __shfl_xor(m,o));
  float den=0.f, wsum=0.f;
  for (int k=beg+l; k<end; k+=64){
    float hs = h2[ssrc[k]];
    float e = hs*as2 + hd; e = (e>0.f)? e : NEG*e;
    float xv = __expf(e-m);
    den += xv; wsum += xv*hs;
  }
  #pragma unroll
  for (int o=32;o>0;o>>=1){ den += __shfl_xor(den,o); wsum += __shfl_xor(wsum,o); }
  if (l==0){
    float z = wsum/den + b2[0];
    out[n] = 1.f/(1.f+__expf(-z));
  }
}

extern "C" void kernel_launch(void* const* d_in, const int* in_sizes, int n_in,
                              void* d_out, int out_size, void* d_ws, size_t ws_size,
                              hipStream_t stream){
  const float* x     = (const float*)d_in[0];
  const int*   ei    = (const int*)d_in[1];
  const float* W1    = (const float*)d_in[2];
  const float* aw_s  = (const float*)d_in[3];
  const float* aw_d  = (const float*)d_in[4];
  const float* b1    = (const float*)d_in[5];
  const float* W2    = (const float*)d_in[6];
  const float* at_s2 = (const float*)d_in[7];
  const float* at_d2 = (const float*)d_in[8];
  const float* b2    = (const float*)d_in[9];
  float* out = (float*)d_out;

  const int N = in_sizes[0]/128;
  const int E = in_sizes[1]/2;
  const int Etot = E + N;

  // workspace layout (~61.3 MB total)
  char* w = (char*)d_ws;
  float* h1  = (float*)w;  w += (size_t)N*128*4;
  float* as1 = (float*)w;  w += (size_t)N*2*4;
  float* ad1 = (float*)w;  w += (size_t)N*2*4;
  float* h2  = (float*)w;  w += (size_t)N*4;
  int* off   = (int*)w;    w += (size_t)(N+1)*4;
  int* cnt   = (int*)w;    w += (size_t)N*4;
  int* cur   = (int*)w;    w += (size_t)N*4;
  int* bsum  = (int*)w;    w += 1024;           // NB <= 128 assumed (N <= 131072)
  int* ssrc  = (int*)w;    w += (size_t)Etot*4;

  const int tb = 256;
  hipMemsetAsync(cnt, 0, (size_t)N*4, stream);
  hist_k<<<(Etot+tb-1)/tb, tb, 0, stream>>>(ei, cnt, E, N);
  int NB = (N+1023)/1024;                       // 98 for N=100000
  scan1_k<<<NB, 256, 0, stream>>>(cnt, off, bsum, N);
  scan2_k<<<1, 128, 0, stream>>>(bsum, NB);
  addoff_k<<<(N+tb-1)/tb, tb, 0, stream>>>(off, bsum, cur, N, Etot);
  scatter_k<<<(Etot+tb-1)/tb, tb, 0, stream>>>(ei, cur, ssrc, E, N);
  gemm_k<<<(N+127)/128, 256, 0, stream>>>(x, W1, h1, N);
  a1_k<<<N, 64, 0, stream>>>(h1, aw_s, aw_d, as1, ad1, N);
  agg1_k<<<N, 64, 0, stream>>>(h1, as1, ad1, off, ssrc, b1, W2, h2, N);
  agg2_k<<<(N+3)/4, 256, 0, stream>>>(h2, off, ssrc, at_s2, at_d2, b2, out, N);
}